// Round 15
// baseline (182.917 us; speedup 1.0000x reference)
//
#include <hip/hip_runtime.h>

// Adaptive separable conv (SepConv): out[b,c,y,x] = sum_i sum_j inp[b,c,y+i,x+j]*v[b,i,y,x]*h[b,j,y,x]
// B=2,C=3,H=W=256,K=51. fp32 in/out. No MFMA path (per-pixel weights; no fp32 MFMA on CDNA4).
//
// R15: R14's barrier-free wave-private h staging, RACE FIXED. R14 failed (absmax 37):
// staging chunk k+3 into slot (k-1)&3 overwrote a slot whose ds_reads were issued only one
// step earlier - lgkm completion of a read is NOT ordered vs a newer DMA write to the same
// LDS address (DS pipe and vmem->LDS DMA are independent). Fixed step (2-ahead, 4-slot ring):
//   s_waitcnt lgkmcnt(0)   // drain ALL prior-step LDS reads (>=1 step old -> near-free)
//   stage chunk k+2        // slot (k+2)&3: consumed at step k-2, reads drained above -> SAFE
//   s_waitcnt vmcnt(4)     // retires exactly stage k (leaves k+1,k+2 = 4 ops in flight)
//   consume chunk k        // 2 h ds_reads + 40 FMA (+4 window refills every 4th step)
// 51 consume-steps + 1 stage-only skip-step per tap-block keeps kStage == kCur+2 and the
// j-ring aligned. NO barriers in the main loop; waves drift (phase-lock theory test).
// Keeps: R12 z-split (z=half*6+bc, 33-row inp slice), 12 waves/CU (48.1KB -> 3 blocks/CU),
// rotation h layout, 3-slot zero-mov windows, 1.25 ops/MAC, launch_bounds(256,1),
// partials in d_ws + tiny sum kernel.

namespace {
constexpr int KK = 51;
constexpr int NB = 2;
constexpr int NC = 3;
constexpr int HH = 256;
constexpr int WW = 256;
constexpr int IN_H = HH + KK - 1;   // 306
constexpr int IN_W = WW + KK - 1;   // 306

constexpr int TILE_W = 64;          // output cols per block
constexpr int TILE_H = 8;           // output rows per block
constexpr int NTX = 8;              // threads along x (each covers R=8 outputs)
constexpr int R = 8;
constexpr int NTY = 8;
constexpr int NS = 4;               // waves per block
constexpr int NTHREADS = NTX * NTY * NS;   // 256
constexpr int HALO_W = TILE_W + KK - 1;    // 114
constexpr int LDS_W = 116;          // 114 valid + 2 slack
constexpr int LDS_H = 33;           // TILE_H-1 + 26 taps/half
constexpr int KSTRIDE = HH * WW;    // per-tap stride in v/h (65536)
constexpr int OUTN = NB * NC * HH * WW;    // 393216 floats per half-partial
}

__device__ __forceinline__ float fget(const float4 v, int i) {
  return (i == 0) ? v.x : (i == 1) ? v.y : (i == 2) ? v.z : v.w;
}

// One j-tap: t = sum_ib v[ib]*w[ib], acc += h*t. P = window phase, JJ = j within period.
template <int P, int JJ>
__device__ __forceinline__ void fma_jtap(const float4 (&v4)[4][2], const float4 (&w4)[4][3],
                                         const float4 ha, const float4 hb, float (&acc)[R]) {
#pragma unroll
  for (int rx = 0; rx < R; ++rx) {
    const int k  = rx + JJ;            // logical window index 0..10
    const int sl = (P + k / 4) % 3;    // physical slot
    const int cp = k & 3;
    const int vh = rx >> 2, vc = rx & 3;
    float tv = fget(v4[0][vh], vc) * fget(w4[0][sl], cp);
    tv = fmaf(fget(v4[1][vh], vc), fget(w4[1][sl], cp), tv);
    tv = fmaf(fget(v4[2][vh], vc), fget(w4[2][sl], cp), tv);
    tv = fmaf(fget(v4[3][vh], vc), fget(w4[3][sl], cp), tv);
    const float hv = (rx < 4) ? fget(ha, vc) : fget(hb, vc);
    acc[rx] = fmaf(hv, tv, acc[rx]);
  }
}

// Consume one 1-j-tap private chunk from LDS (rotated layout) and accumulate.
template <int P, int JJ>
__device__ __forceinline__ void chunk_fma(const float4 (&v4)[4][2], const float4 (&w4)[4][3],
                                          const float* hb, int off0, int off1,
                                          float (&acc)[R]) {
  const float4 ha  = *reinterpret_cast<const float4*>(hb + off0);
  const float4 hbv = *reinterpret_cast<const float4*>(hb + off1);
  fma_jtap<P, JJ>(v4, w4, ha, hbv, acc);
}

__global__ __launch_bounds__(NTHREADS, 1)
void sepconv_kernel(
    const float* __restrict__ inp,
    const float* __restrict__ vert,
    const float* __restrict__ horiz,
    float* __restrict__ ws)
{
  __shared__ float lds[LDS_H * LDS_W];     // 15,312 B (inp slice; reused for reduction)
  __shared__ float hbw[NS * 4 * 512];      // 32,768 B (per-wave 4-slot h ring, 2KB/slot)

  const int tid  = threadIdx.x;
  const int tx   = tid & (NTX - 1);
  const int ty   = (tid >> 3) & (NTY - 1);
  const int s    = tid >> 6;                   // wave id: 0..3 (wave-uniform)
  const int lane = tid & 63;

  const int x0 = blockIdx.x * TILE_W;
  const int y0 = blockIdx.y * TILE_H;
  const int zz = blockIdx.z;                   // 0..11
  const int bc = zz % (NB * NC);               // 0..5
  const int half = zz / (NB * NC);             // 0..1
  const int b  = bc / NC;
  const int c  = bc % NC;

  const int ROWBASE = half * 26;               // first i-tap of this half
  const int ROWMAX  = half ? 50 : 25;          // last real i-tap of this half

  // ---- Stage input slice: rows y0+ROWBASE .. +32 (clamped), 114 cols (float2).
  {
    const float* src = inp + (((size_t)(b * NC + c)) * IN_H) * IN_W + x0;
    constexpr int total2 = LDS_H * (HALO_W / 2);   // 33*57 = 1881
    for (int e = tid; e < total2; e += NTHREADS) {
      const int col2 = e % (HALO_W / 2);
      const int r    = e / (HALO_W / 2);
      const int gr   = min(y0 + ROWBASE + r, IN_H - 1);
      const float2 v = *reinterpret_cast<const float2*>(src + (size_t)gr * IN_W + col2 * 2);
      float* dst = &lds[r * LDS_W + col2 * 2];
      dst[0] = v.x; dst[1] = v.y;
    }
  }

  // ---- Wave-private h staging. Chunk = 1 j-tap = 8 rows x 64 cols = 2KB = 2 DMA instr.
  // Slot p = r*64 + lane (r=0,1): row=p>>4, c4=p&15; holds global quad q=(c4-row)&15
  // (per-row rotation so the consuming b128 read hits the bank floor).
  const float* hblk = horiz + (((size_t)b * KK) * HH + y0) * WW + x0;
  int goffr[2];
#pragma unroll
  for (int r = 0; r < 2; ++r) {
    const int p   = r * 64 + lane;
    const int row = p >> 4;                    // 0..7
    const int q   = ((p & 15) - row) & 15;
    goffr[r] = row * WW + q * 4;
  }
  float* mybuf = &hbw[s * 2048];               // this wave's 4-slot ring

  int kStage = 0;   // next chunk index to stage (slot = kStage&3); invariant: kStage==kCur+2
  int jS     = 0;   // kStage % 52 (the j of that chunk; j=51 clamped, data never consumed)
  auto stageK = [&]() {
    const int j = (jS <= 50) ? jS : 50;
    const float* g0 = hblk + (size_t)j * KSTRIDE;
    float* dst = mybuf + (kStage & 3) * 512;
#pragma unroll
    for (int r = 0; r < 2; ++r)
      __builtin_amdgcn_global_load_lds(
          (const __attribute__((address_space(1))) void*)(g0 + goffr[r]),
          (__attribute__((address_space(3))) void*)(dst + r * 256), 16, 0, 0);
    ++kStage;
    if (++jS == 52) jS = 0;
  };

  // Prologue: chunks 0,1 in flight; the ONLY barrier before the reduction.
  stageK(); stageK();
  __syncthreads();           // drains inp staging + the 2 prologue DMAs
  int kCur = 0;              // chunk being consumed; slot = kCur&3

  const int lx = tx * R;                 // local LDS col base (32B aligned)
  const int xg = x0 + lx;
  const int yg = y0 + ty;

  // Rotated h read offsets within a 512-float tap chunk: row ty, quads 2tx, 2tx+1.
  const int off0 = ty * 64 + ((2 * tx + ty) & 15) * 4;
  const int off1 = ty * 64 + ((2 * tx + 1 + ty) & 15) * 4;

  float acc[R];
#pragma unroll
  for (int rx = 0; rx < R; ++rx) acc[rx] = 0.f;

  // Deal 7 BI=4 tap-blocks (28 virtual taps of this half) to 4 waves: 2/2/2/1.
  // No uniform-trip requirement: the main loop has NO barriers.
  const int blk0 = (s < 3) ? 2 * s : 6;
  const int nblk = (s < 3) ? 2 : 1;

  const float* vbase = vert + (((size_t)b * KK) * HH + yg) * WW + xg;

// Step k: drain prior LDS reads (slot k+2's old readers included -> overwrite-safe),
// stage k+2, retire stage k via counted vmcnt, consume chunk k.
#define CSTEP_PRE()                                                           \
    asm volatile("s_waitcnt lgkmcnt(0)" ::: "memory");                        \
    stageK();                                                                 \
    asm volatile("s_waitcnt vmcnt(4)" ::: "memory");

#define CSTEPN(PP, JJ)                                                        \
  {                                                                           \
    CSTEP_PRE();                                                              \
    chunk_fma<PP, JJ>(v4, w4, mybuf + (kCur & 3) * 512, off0, off1, acc);     \
    ++kCur;                                                                   \
  }
#define CSTEPR(PP, WCOL)                                                      \
  {                                                                           \
    CSTEP_PRE();                                                              \
    chunk_fma<PP, 3>(v4, w4, mybuf + (kCur & 3) * 512, off0, off1, acc);      \
    _Pragma("unroll")                                                         \
    for (int ib = 0; ib < 4; ++ib)                                            \
      w4[ib][PP] = *reinterpret_cast<const float4*>(&lds[woff[ib] + (WCOL)]); \
    ++kCur;                                                                   \
  }

#pragma unroll 1
  for (int t = 0; t < nblk; ++t) {
    const int ibase = ROWBASE + (blk0 + t) * 4;
    float4 v4[4][2];
    float4 w4[4][3];
    int    woff[4];
#pragma unroll
    for (int ib = 0; ib < 4; ++ib) {
      const int iv = ibase + ib;                 // may exceed ROWMAX (virtual tap)
      const int ic = (iv <= ROWMAX) ? iv : ROWMAX;
      float4 va = *reinterpret_cast<const float4*>(vbase + (size_t)ic * KSTRIDE);
      float4 vb = *reinterpret_cast<const float4*>(vbase + (size_t)ic * KSTRIDE + 4);
      if (iv > ROWMAX) { va = make_float4(0.f, 0.f, 0.f, 0.f); vb = va; }
      v4[ib][0] = va; v4[ib][1] = vb;
      woff[ib] = (ty + ic - ROWBASE) * LDS_W;    // row <= 32
      const float4* p = reinterpret_cast<const float4*>(&lds[woff[ib] + lx]);
      w4[ib][0] = p[0]; w4[ib][1] = p[1]; w4[ib][2] = p[2];
    }

    // 12 full periods (4 j-taps each; phase advances per period) + epilogue period.
#pragma unroll 1
    for (int g2 = 0; g2 < 4; ++g2) {
      const int cb = lx + 12 * g2 + 12;
      CSTEPN(0, 0); CSTEPN(0, 1); CSTEPN(0, 2); CSTEPR(0, cb + 0);
      CSTEPN(1, 0); CSTEPN(1, 1); CSTEPN(1, 2); CSTEPR(1, cb + 4);
      CSTEPN(2, 0); CSTEPN(2, 1); CSTEPN(2, 2); CSTEPR(2, cb + 8);
    }
    // Epilogue period (P0): consume j=48,49,50; then one stage-only skip-step to keep
    // the kStage == kCur+2 invariant and the 52-chunk j-ring alignment.
    CSTEPN(0, 0); CSTEPN(0, 1); CSTEPN(0, 2);
    {
      asm volatile("s_waitcnt lgkmcnt(0)" ::: "memory");
      stageK();
      ++kCur;
    }
  }
#undef CSTEPN
#undef CSTEPR
#undef CSTEP_PRE

  // ---- Reduce the 4 wave partials (waves 1..3 -> LDS inp region, wave 0 adds & stores)
  __syncthreads();   // drains dead tail DMAs + orders all inp-tile reads before reuse
  if (s > 0) {
    float* p = &lds[((s - 1) * 64 + ty * NTX + tx) * R];
#pragma unroll
    for (int rx = 0; rx < R; ++rx) p[rx] = acc[rx];
  }
  __syncthreads();
  if (s == 0) {
#pragma unroll
    for (int g = 0; g < 3; ++g) {
      const float* p = &lds[(g * 64 + ty * NTX + tx) * R];
#pragma unroll
      for (int rx = 0; rx < R; ++rx) acc[rx] += p[rx];
    }
    float* o = ws + (size_t)half * OUTN + (((size_t)(b * NC + c)) * HH + yg) * WW + xg;
    *reinterpret_cast<float4*>(o)     = make_float4(acc[0], acc[1], acc[2], acc[3]);
    *reinterpret_cast<float4*>(o + 4) = make_float4(acc[4], acc[5], acc[6], acc[7]);
  }
}

// Sum the two i-half partials into the output. 98304 float4 elements.
__global__ __launch_bounds__(256)
void sum_halves(const float4* __restrict__ a, const float4* __restrict__ b,
                float4* __restrict__ o)
{
  const int i = blockIdx.x * 256 + threadIdx.x;   // grid sized exactly
  const float4 x = a[i], y = b[i];
  o[i] = make_float4(x.x + y.x, x.y + y.y, x.z + y.z, x.w + y.w);
}

extern "C" void kernel_launch(void* const* d_in, const int* in_sizes, int n_in,
                              void* d_out, int out_size, void* d_ws, size_t ws_size,
                              hipStream_t stream) {
  const float* inp   = (const float*)d_in[0];
  const float* vert  = (const float*)d_in[1];
  const float* horiz = (const float*)d_in[2];
  float* out = (float*)d_out;
  float* ws  = (float*)d_ws;                      // needs 2 * 393216 floats = 3.15 MB

  dim3 grid(WW / TILE_W, HH / TILE_H, 2 * NB * NC);   // 4 x 32 x 12 = 1536 blocks
  sepconv_kernel<<<grid, NTHREADS, 0, stream>>>(inp, vert, horiz, ws);

  const int n4 = OUTN / 4;                        // 98304
  sum_halves<<<n4 / 256, 256, 0, stream>>>(
      (const float4*)ws, (const float4*)(ws + OUTN), (float4*)out);
}